// Round 8
// baseline (75.001 us; speedup 1.0000x reference)
//
#include <hip/hip_runtime.h>
#include <math.h>

#define HALF_LOG_2PI_F 0.9189385332046727f

typedef float f32x4 __attribute__((ext_vector_type(4)));

// ---------------------------------------------------------------------------
// Kernel 1 (prep, single block of 1024): per-feature quadratic coefficients.
//   A[k] = deg * (-0.5 / s^2);  B[k] = deg * (m / s^2)
//   Csum = sum_k deg * (-0.5*m^2/s^2 - log(s) - HALF_LOG_2PI)
// ---------------------------------------------------------------------------
__global__ void clt_prep_kernel(const float* __restrict__ rp,
                                const int* __restrict__ edges,
                                float* __restrict__ A,
                                float* __restrict__ B,
                                float* __restrict__ csum,
                                int D, int E) {
    extern __shared__ float sdeg[];
    for (int k = threadIdx.x; k < D; k += blockDim.x) sdeg[k] = 0.0f;
    __syncthreads();
    for (int e = threadIdx.x; e < E; e += blockDim.x) {
        atomicAdd(&sdeg[edges[2 * e]], 1.0f);      // integer-valued: exact
        atomicAdd(&sdeg[edges[2 * e + 1]], 1.0f);
    }
    __syncthreads();
    float local_c = 0.0f;
    for (int k = threadIdx.x; k < D; k += blockDim.x) {
        float m = tanhf(rp[k]) * 2.0f;
        float sx = rp[D + k];
        float s = fmaxf(sx, 0.0f) + log1pf(expf(-fabsf(sx))) + 1e-6f;
        float inv_s2 = 1.0f / (s * s);
        float deg = sdeg[k];
        A[k] = deg * (-0.5f * inv_s2);
        B[k] = deg * (m * inv_s2);
        local_c += deg * (-0.5f * m * m * inv_s2 - logf(s) - HALF_LOG_2PI_F);
    }
    __shared__ float wsum[16];
    for (int off = 32; off > 0; off >>= 1)
        local_c += __shfl_down(local_c, off, 64);
    if ((threadIdx.x & 63) == 0) wsum[threadIdx.x >> 6] = local_c;
    __syncthreads();
    if (threadIdx.x == 0) {
        float t = 0.0f;
        int nw = (blockDim.x + 63) >> 6;
        for (int w = 0; w < nw; ++w) t += wsum[w];
        *csum = t;
    }
}

// ---------------------------------------------------------------------------
// Kernel 2 (main): ONE WAVE PER ROW-PAIR, grid-strided. Plain (cacheable)
// loads — x fits in L3 and stays resident across replays. A/B float4
// fragments in registers, loaded once per wave. No LDS, no __syncthreads
// in the streaming path. __launch_bounds__(256,4) caps VGPR at 128 so all
// 4 blocks/CU (16 waves/CU) are resident.
// ---------------------------------------------------------------------------
template <int NI>
__global__ __launch_bounds__(256, 4) void clt_rows2(
        const float* __restrict__ x,
        const float* __restrict__ A,
        const float* __restrict__ B,
        const float* __restrict__ csum,
        float* __restrict__ out,
        int D, int N, int total_waves) {
    const int lane = threadIdx.x & 63;
    const int gwave = blockIdx.x * 4 + (threadIdx.x >> 6);

    const f32x4* Av = (const f32x4*)A;
    const f32x4* Bv = (const f32x4*)B;
    f32x4 a4[NI], b4[NI];
#pragma unroll
    for (int i = 0; i < NI; ++i) {
        a4[i] = Av[i * 64 + lane];
        b4[i] = Bv[i * 64 + lane];
    }
    const float c = *csum;

    for (int r = gwave * 2; r < N; r += total_waves * 2) {
        const f32x4* xv0 = (const f32x4*)(x + (size_t)r * (size_t)D);
        const f32x4* xv1 = (const f32x4*)(x + (size_t)(r + 1) * (size_t)D);
        float p0 = 0.0f, q0 = 0.0f, p1 = 0.0f, q1 = 0.0f;
#pragma unroll
        for (int i = 0; i < NI; ++i) {
            f32x4 x0 = xv0[i * 64 + lane];
            f32x4 x1 = xv1[i * 64 + lane];
            p0 += x0.x * fmaf(a4[i].x, x0.x, b4[i].x);
            q0 += x0.y * fmaf(a4[i].y, x0.y, b4[i].y);
            p0 += x0.z * fmaf(a4[i].z, x0.z, b4[i].z);
            q0 += x0.w * fmaf(a4[i].w, x0.w, b4[i].w);
            p1 += x1.x * fmaf(a4[i].x, x1.x, b4[i].x);
            q1 += x1.y * fmaf(a4[i].y, x1.y, b4[i].y);
            p1 += x1.z * fmaf(a4[i].z, x1.z, b4[i].z);
            q1 += x1.w * fmaf(a4[i].w, x1.w, b4[i].w);
        }
        float acc0 = p0 + q0;
        float acc1 = p1 + q1;
#pragma unroll
        for (int off = 32; off > 0; off >>= 1) {
            acc0 += __shfl_down(acc0, off, 64);
            acc1 += __shfl_down(acc1, off, 64);
        }
        if (lane == 0) {
            out[r] = acc0 + c;
            out[r + 1] = acc1 + c;   // N even; r even
        }
    }
}

// Generic fallback (any D): block-per-row.
__global__ __launch_bounds__(256) void clt_row_generic(
        const float* __restrict__ x,
        const float* __restrict__ A,
        const float* __restrict__ B,
        const float* __restrict__ csum,
        float* __restrict__ out,
        int D) {
    const int row = blockIdx.x;
    float acc = 0.0f;
    for (int k = threadIdx.x; k < D; k += blockDim.x) {
        float xs = x[(size_t)row * (size_t)D + k];
        acc += xs * fmaf(A[k], xs, B[k]);
    }
    for (int off = 32; off > 0; off >>= 1)
        acc += __shfl_down(acc, off, 64);
    __shared__ float wsum[4];
    if ((threadIdx.x & 63) == 0) wsum[threadIdx.x >> 6] = acc;
    __syncthreads();
    if (threadIdx.x == 0)
        out[row] = wsum[0] + wsum[1] + wsum[2] + wsum[3] + *csum;
}

extern "C" void kernel_launch(void* const* d_in, const int* in_sizes, int n_in,
                              void* d_out, int out_size, void* d_ws, size_t ws_size,
                              hipStream_t stream) {
    const float* x     = (const float*)d_in[0];
    const float* rp    = (const float*)d_in[1];
    const int*   edges = (const int*)d_in[2];
    float* out = (float*)d_out;

    const int D = in_sizes[1] / 2;       // 2048
    const int E = in_sizes[2] / 2;       // D-1
    const int N = out_size;              // 16384 rows

    float* A    = (float*)d_ws;          // [D]
    float* B    = A + D;                 // [D]
    float* csum = B + D;                 // [1]

    clt_prep_kernel<<<1, 1024, D * sizeof(float), stream>>>(rp, edges, A, B, csum, D, E);

    const int NI = D / 256;
    if (D % 256 == 0 && N % 2 == 0 &&
        (NI == 2 || NI == 4 || NI == 8 || NI == 16)) {
        // 1024 blocks = 4 blocks/CU (16 waves/CU, fully resident at <=128 VGPR)
        // 4096 waves x 4 rows (2 iters of 2 rows) = 16384 rows, perfectly balanced
        const int blocks = 1024;
        const int total_waves = blocks * 4;
        switch (NI) {
            case 2:  clt_rows2<2><<<blocks, 256, 0, stream>>>(x, A, B, csum, out, D, N, total_waves); break;
            case 4:  clt_rows2<4><<<blocks, 256, 0, stream>>>(x, A, B, csum, out, D, N, total_waves); break;
            case 8:  clt_rows2<8><<<blocks, 256, 0, stream>>>(x, A, B, csum, out, D, N, total_waves); break;
            default: clt_rows2<16><<<blocks, 256, 0, stream>>>(x, A, B, csum, out, D, N, total_waves); break;
        }
    } else {
        clt_row_generic<<<N, 256, 0, stream>>>(x, A, B, csum, out, D);
    }
}

// Round 9
// 36.277 us; speedup vs baseline: 2.0675x; 2.0675x over previous
//
#include <hip/hip_runtime.h>
#include <math.h>

#define HALF_LOG_2PI_F 0.9189385332046727f

typedef float f32x4 __attribute__((ext_vector_type(4)));

// ---------------------------------------------------------------------------
// Kernel 1 (prep, single block of 1024): per-feature quadratic coefficients.
//   A[k] = deg * (-0.5 / s^2);  B[k] = deg * (m / s^2)
//   Csum = sum_k deg * (-0.5*m^2/s^2 - log(s) - HALF_LOG_2PI)
// ---------------------------------------------------------------------------
__global__ void clt_prep_kernel(const float* __restrict__ rp,
                                const int* __restrict__ edges,
                                float* __restrict__ A,
                                float* __restrict__ B,
                                float* __restrict__ csum,
                                int D, int E) {
    extern __shared__ float sdeg[];
    for (int k = threadIdx.x; k < D; k += blockDim.x) sdeg[k] = 0.0f;
    __syncthreads();
    for (int e = threadIdx.x; e < E; e += blockDim.x) {
        atomicAdd(&sdeg[edges[2 * e]], 1.0f);      // integer-valued: exact
        atomicAdd(&sdeg[edges[2 * e + 1]], 1.0f);
    }
    __syncthreads();
    float local_c = 0.0f;
    for (int k = threadIdx.x; k < D; k += blockDim.x) {
        float m = tanhf(rp[k]) * 2.0f;
        float sx = rp[D + k];
        float s = fmaxf(sx, 0.0f) + log1pf(expf(-fabsf(sx))) + 1e-6f;
        float inv_s2 = 1.0f / (s * s);
        float deg = sdeg[k];
        A[k] = deg * (-0.5f * inv_s2);
        B[k] = deg * (m * inv_s2);
        local_c += deg * (-0.5f * m * m * inv_s2 - logf(s) - HALF_LOG_2PI_F);
    }
    __shared__ float wsum[16];
    for (int off = 32; off > 0; off >>= 1)
        local_c += __shfl_down(local_c, off, 64);
    if ((threadIdx.x & 63) == 0) wsum[threadIdx.x >> 6] = local_c;
    __syncthreads();
    if (threadIdx.x == 0) {
        float t = 0.0f;
        int nw = (blockDim.x + 63) >> 6;
        for (int w = 0; w < nw; ++w) t += wsum[w];
        *csum = t;
    }
}

// ---------------------------------------------------------------------------
// Kernel 2 (main): COLUMN-SLICE decomposition for minimal VGPR state.
//   Block = 4 waves; wave w owns columns [w*NI*256, (w+1)*NI*256) (NI float4
//   per lane -> a4/b4 = 2*NI float4 = 16 VGPR at NI=2). Block b processes
//   rows 8b..8b+7. Per (row, slice): NI coalesced float4 loads, FMA dot,
//   6-shuffle wave reduce -> lds[row][w]; one barrier; threads 0..7 sum the
//   4 slice-partials + csum -> out. __launch_bounds__(256,8) pins <=64 VGPR
//   so 8 waves/SIMD can be resident (grid 2048 = 8 blocks/CU = 32 waves/CU).
//   Requires D == NI*1024, N % 8 == 0.
// ---------------------------------------------------------------------------
template <int NI>
__global__ __launch_bounds__(256, 8) void clt_slice(
        const float* __restrict__ x,
        const float* __restrict__ A,
        const float* __restrict__ B,
        const float* __restrict__ csum,
        float* __restrict__ out,
        int D, int N, int nblocks) {
    const int lane = threadIdx.x & 63;
    const int w = threadIdx.x >> 6;            // slice id 0..3
    const int colbase = w * (NI * 64);         // slice start, float4 units

    const f32x4* Av = (const f32x4*)A;
    const f32x4* Bv = (const f32x4*)B;
    f32x4 a4[NI], b4[NI];
#pragma unroll
    for (int i = 0; i < NI; ++i) {
        a4[i] = Av[colbase + i * 64 + lane];
        b4[i] = Bv[colbase + i * 64 + lane];
    }
    const float c = *csum;

    __shared__ float lds[8][4];

    for (int rb = blockIdx.x; rb * 8 < N; rb += nblocks) {
        const int r0 = rb * 8;
#pragma unroll 2
        for (int r = 0; r < 8; ++r) {
            const f32x4* xv = (const f32x4*)(x + (size_t)(r0 + r) * (size_t)D)
                              + colbase;
            float p = 0.0f, q = 0.0f;
#pragma unroll
            for (int i = 0; i < NI; ++i) {
                f32x4 xq = xv[i * 64 + lane];
                p += xq.x * fmaf(a4[i].x, xq.x, b4[i].x);
                q += xq.y * fmaf(a4[i].y, xq.y, b4[i].y);
                p += xq.z * fmaf(a4[i].z, xq.z, b4[i].z);
                q += xq.w * fmaf(a4[i].w, xq.w, b4[i].w);
            }
            float acc = p + q;
#pragma unroll
            for (int off = 32; off > 0; off >>= 1)
                acc += __shfl_down(acc, off, 64);
            if (lane == 0) lds[r][w] = acc;
        }
        __syncthreads();
        if (threadIdx.x < 8) {
            out[r0 + threadIdx.x] = lds[threadIdx.x][0] + lds[threadIdx.x][1]
                                  + lds[threadIdx.x][2] + lds[threadIdx.x][3]
                                  + c;
        }
        __syncthreads();   // protect lds before next batch (no-op if 1 iter)
    }
}

// Generic fallback (any D): block-per-row.
__global__ __launch_bounds__(256) void clt_row_generic(
        const float* __restrict__ x,
        const float* __restrict__ A,
        const float* __restrict__ B,
        const float* __restrict__ csum,
        float* __restrict__ out,
        int D) {
    const int row = blockIdx.x;
    float acc = 0.0f;
    for (int k = threadIdx.x; k < D; k += blockDim.x) {
        float xs = x[(size_t)row * (size_t)D + k];
        acc += xs * fmaf(A[k], xs, B[k]);
    }
    for (int off = 32; off > 0; off >>= 1)
        acc += __shfl_down(acc, off, 64);
    __shared__ float wsum[4];
    if ((threadIdx.x & 63) == 0) wsum[threadIdx.x >> 6] = acc;
    __syncthreads();
    if (threadIdx.x == 0)
        out[row] = wsum[0] + wsum[1] + wsum[2] + wsum[3] + *csum;
}

extern "C" void kernel_launch(void* const* d_in, const int* in_sizes, int n_in,
                              void* d_out, int out_size, void* d_ws, size_t ws_size,
                              hipStream_t stream) {
    const float* x     = (const float*)d_in[0];
    const float* rp    = (const float*)d_in[1];
    const int*   edges = (const int*)d_in[2];
    float* out = (float*)d_out;

    const int D = in_sizes[1] / 2;       // 2048
    const int E = in_sizes[2] / 2;       // D-1
    const int N = out_size;              // 16384 rows

    float* A    = (float*)d_ws;          // [D]
    float* B    = A + D;                 // [D]
    float* csum = B + D;                 // [1]

    clt_prep_kernel<<<1, 1024, D * sizeof(float), stream>>>(rp, edges, A, B, csum, D, E);

    const int NI = D / 1024;             // float4s per lane per slice
    if (N % 8 == 0 && D == NI * 1024 && (NI == 1 || NI == 2 || NI == 4)) {
        int nblocks = N / 8;             // one 8-row batch per block
        if (nblocks > 2048) nblocks = 2048;   // 8 blocks/CU; grid-stride rest
        switch (NI) {
            case 1:  clt_slice<1><<<nblocks, 256, 0, stream>>>(x, A, B, csum, out, D, N, nblocks); break;
            case 2:  clt_slice<2><<<nblocks, 256, 0, stream>>>(x, A, B, csum, out, D, N, nblocks); break;
            default: clt_slice<4><<<nblocks, 256, 0, stream>>>(x, A, B, csum, out, D, N, nblocks); break;
        }
    } else {
        clt_row_generic<<<N, 256, 0, stream>>>(x, A, B, csum, out, D);
    }
}

// Round 10
// 35.510 us; speedup vs baseline: 2.1121x; 1.0216x over previous
//
#include <hip/hip_runtime.h>
#include <math.h>

#define HALF_LOG_2PI_F 0.9189385332046727f

typedef float f32x4 __attribute__((ext_vector_type(4)));

// ---------------------------------------------------------------------------
// Kernel 1 (prep, single block of 1024): per-feature quadratic coefficients.
//   A[k] = deg * (-0.5 / s^2);  B[k] = deg * (m / s^2)
//   Csum = sum_k deg * (-0.5*m^2/s^2 - log(s) - HALF_LOG_2PI)
// R8 evidence: this launch costs <~2 us inside the graph — not worth fusing.
// ---------------------------------------------------------------------------
__global__ void clt_prep_kernel(const float* __restrict__ rp,
                                const int* __restrict__ edges,
                                float* __restrict__ A,
                                float* __restrict__ B,
                                float* __restrict__ csum,
                                int D, int E) {
    extern __shared__ float sdeg[];
    for (int k = threadIdx.x; k < D; k += blockDim.x) sdeg[k] = 0.0f;
    __syncthreads();
    for (int e = threadIdx.x; e < E; e += blockDim.x) {
        atomicAdd(&sdeg[edges[2 * e]], 1.0f);      // integer-valued: exact
        atomicAdd(&sdeg[edges[2 * e + 1]], 1.0f);
    }
    __syncthreads();
    float local_c = 0.0f;
    for (int k = threadIdx.x; k < D; k += blockDim.x) {
        float m = tanhf(rp[k]) * 2.0f;
        float sx = rp[D + k];
        float s = fmaxf(sx, 0.0f) + log1pf(expf(-fabsf(sx))) + 1e-6f;
        float inv_s2 = 1.0f / (s * s);
        float deg = sdeg[k];
        A[k] = deg * (-0.5f * inv_s2);
        B[k] = deg * (m * inv_s2);
        local_c += deg * (-0.5f * m * m * inv_s2 - logf(s) - HALF_LOG_2PI_F);
    }
    __shared__ float wsum[16];
    for (int off = 32; off > 0; off >>= 1)
        local_c += __shfl_down(local_c, off, 64);
    if ((threadIdx.x & 63) == 0) wsum[threadIdx.x >> 6] = local_c;
    __syncthreads();
    if (threadIdx.x == 0) {
        float t = 0.0f;
        int nw = (blockDim.x + 63) >> 6;
        for (int w = 0; w < nw; ++w) t += wsum[w];
        *csum = t;
    }
}

// ---------------------------------------------------------------------------
// Kernel 2 (main): slice decomposition + 8-ROW BATCH with DEFERRED reduction.
//   Wave w owns columns [w*NI*256, (w+1)*NI*256); block b owns rows 8b..8b+7.
//   Phase 1: issue ALL 8*NI float4 x-loads into registers (independent, max
//            loads in flight), FMA-accumulate 8 per-row partials.
//   Phase 2: 8 interleaved 6-level shuffle reductions (independent chains).
//   Phase 3: lane0 -> lds[8][4], barrier, threads 0..7 sum 4 slices + csum.
//   No launch_bounds VGPR cap (R8 showed capping makes the compiler refuse
//   to hoist/pipeline). Expect ~110-130 VGPR -> 4 waves/SIMD.
//   Requires D == NI*1024, N % 8 == 0. Grid = N/8 blocks exactly.
// ---------------------------------------------------------------------------
template <int NI>
__global__ __launch_bounds__(256) void clt_slice8(
        const float* __restrict__ x,
        const float* __restrict__ A,
        const float* __restrict__ B,
        const float* __restrict__ csum,
        float* __restrict__ out,
        int D) {
    const int lane = threadIdx.x & 63;
    const int w = threadIdx.x >> 6;            // slice id 0..3
    const int colbase = w * (NI * 64);         // slice start, float4 units
    const int rowstride = D >> 2;              // float4 per row

    const f32x4* Av = (const f32x4*)A;
    const f32x4* Bv = (const f32x4*)B;
    f32x4 a4[NI], b4[NI];
#pragma unroll
    for (int i = 0; i < NI; ++i) {
        a4[i] = Av[colbase + i * 64 + lane];
        b4[i] = Bv[colbase + i * 64 + lane];
    }
    const float c = *csum;

    const int r0 = blockIdx.x * 8;
    const f32x4* xv = (const f32x4*)(x + (size_t)r0 * (size_t)D)
                      + colbase + lane;

    // Phase 1: all loads first (static indices -> registers), then FMAs.
    f32x4 xr[8][NI];
#pragma unroll
    for (int r = 0; r < 8; ++r)
#pragma unroll
        for (int i = 0; i < NI; ++i)
            xr[r][i] = xv[(size_t)r * rowstride + i * 64];

    float acc[8];
#pragma unroll
    for (int r = 0; r < 8; ++r) {
        float p = 0.0f, q = 0.0f;
#pragma unroll
        for (int i = 0; i < NI; ++i) {
            f32x4 xq = xr[r][i];
            p += xq.x * fmaf(a4[i].x, xq.x, b4[i].x);
            q += xq.y * fmaf(a4[i].y, xq.y, b4[i].y);
            p += xq.z * fmaf(a4[i].z, xq.z, b4[i].z);
            q += xq.w * fmaf(a4[i].w, xq.w, b4[i].w);
        }
        acc[r] = p + q;
    }

    // Phase 2: interleaved reductions — 8 independent chains per level.
#pragma unroll
    for (int off = 32; off > 0; off >>= 1) {
#pragma unroll
        for (int r = 0; r < 8; ++r)
            acc[r] += __shfl_down(acc[r], off, 64);
    }

    // Phase 3: cross-wave combine via tiny LDS.
    __shared__ float lds[8][4];
    if (lane == 0) {
#pragma unroll
        for (int r = 0; r < 8; ++r) lds[r][w] = acc[r];
    }
    __syncthreads();
    if (threadIdx.x < 8) {
        out[r0 + threadIdx.x] = lds[threadIdx.x][0] + lds[threadIdx.x][1]
                              + lds[threadIdx.x][2] + lds[threadIdx.x][3]
                              + c;
    }
}

// Generic fallback (any D): block-per-row.
__global__ __launch_bounds__(256) void clt_row_generic(
        const float* __restrict__ x,
        const float* __restrict__ A,
        const float* __restrict__ B,
        const float* __restrict__ csum,
        float* __restrict__ out,
        int D) {
    const int row = blockIdx.x;
    float acc = 0.0f;
    for (int k = threadIdx.x; k < D; k += blockDim.x) {
        float xs = x[(size_t)row * (size_t)D + k];
        acc += xs * fmaf(A[k], xs, B[k]);
    }
    for (int off = 32; off > 0; off >>= 1)
        acc += __shfl_down(acc, off, 64);
    __shared__ float wsum[4];
    if ((threadIdx.x & 63) == 0) wsum[threadIdx.x >> 6] = acc;
    __syncthreads();
    if (threadIdx.x == 0)
        out[row] = wsum[0] + wsum[1] + wsum[2] + wsum[3] + *csum;
}

extern "C" void kernel_launch(void* const* d_in, const int* in_sizes, int n_in,
                              void* d_out, int out_size, void* d_ws, size_t ws_size,
                              hipStream_t stream) {
    const float* x     = (const float*)d_in[0];
    const float* rp    = (const float*)d_in[1];
    const int*   edges = (const int*)d_in[2];
    float* out = (float*)d_out;

    const int D = in_sizes[1] / 2;       // 2048
    const int E = in_sizes[2] / 2;       // D-1
    const int N = out_size;              // 16384 rows

    float* A    = (float*)d_ws;          // [D]
    float* B    = A + D;                 // [D]
    float* csum = B + D;                 // [1]

    clt_prep_kernel<<<1, 1024, D * sizeof(float), stream>>>(rp, edges, A, B, csum, D, E);

    const int NI = D / 1024;             // float4s per lane per slice
    if (N % 8 == 0 && D == NI * 1024 && (NI == 1 || NI == 2 || NI == 4)) {
        const int nblocks = N / 8;       // one 8-row batch per block (2048)
        switch (NI) {
            case 1:  clt_slice8<1><<<nblocks, 256, 0, stream>>>(x, A, B, csum, out, D); break;
            case 2:  clt_slice8<2><<<nblocks, 256, 0, stream>>>(x, A, B, csum, out, D); break;
            default: clt_slice8<4><<<nblocks, 256, 0, stream>>>(x, A, B, csum, out, D); break;
        }
    } else {
        clt_row_generic<<<N, 256, 0, stream>>>(x, A, B, csum, out, D);
    }
}

// Round 11
// 33.618 us; speedup vs baseline: 2.2310x; 1.0563x over previous
//
#include <hip/hip_runtime.h>
#include <math.h>

#define HALF_LOG_2PI_F 0.9189385332046727f

typedef float f32x4 __attribute__((ext_vector_type(4)));

// ---------------------------------------------------------------------------
// Kernel 1 (prep, single block of 1024): per-feature quadratic coefficients.
//   A[k] = deg * (-0.5 / s^2);  B[k] = deg * (m / s^2)
//   Csum = sum_k deg * (-0.5*m^2/s^2 - log(s) - HALF_LOG_2PI)
// R8 evidence: this launch costs <~2 us inside the graph — not worth fusing.
// ---------------------------------------------------------------------------
__global__ void clt_prep_kernel(const float* __restrict__ rp,
                                const int* __restrict__ edges,
                                float* __restrict__ A,
                                float* __restrict__ B,
                                float* __restrict__ csum,
                                int D, int E) {
    extern __shared__ float sdeg[];
    for (int k = threadIdx.x; k < D; k += blockDim.x) sdeg[k] = 0.0f;
    __syncthreads();
    for (int e = threadIdx.x; e < E; e += blockDim.x) {
        atomicAdd(&sdeg[edges[2 * e]], 1.0f);      // integer-valued: exact
        atomicAdd(&sdeg[edges[2 * e + 1]], 1.0f);
    }
    __syncthreads();
    float local_c = 0.0f;
    for (int k = threadIdx.x; k < D; k += blockDim.x) {
        float m = tanhf(rp[k]) * 2.0f;
        float sx = rp[D + k];
        float s = fmaxf(sx, 0.0f) + log1pf(expf(-fabsf(sx))) + 1e-6f;
        float inv_s2 = 1.0f / (s * s);
        float deg = sdeg[k];
        A[k] = deg * (-0.5f * inv_s2);
        B[k] = deg * (m * inv_s2);
        local_c += deg * (-0.5f * m * m * inv_s2 - logf(s) - HALF_LOG_2PI_F);
    }
    __shared__ float wsum[16];
    for (int off = 32; off > 0; off >>= 1)
        local_c += __shfl_down(local_c, off, 64);
    if ((threadIdx.x & 63) == 0) wsum[threadIdx.x >> 6] = local_c;
    __syncthreads();
    if (threadIdx.x == 0) {
        float t = 0.0f;
        int nw = (blockDim.x + 63) >> 6;
        for (int w = 0; w < nw; ++w) t += wsum[w];
        *csum = t;
    }
}

// ---------------------------------------------------------------------------
// Kernel 2 (main): R10's slice8 structure, ONE change — x loads are
// NONTEMPORAL (no cache allocation). Theory under test: our read
// allocations evict the harness fill's dirty L3 lines, dragging ~65 MB of
// writeback into our timed window (seen in R8's WRITE_SIZE). nt reads skip
// L3 allocation -> no eviction -> writeback leaves our window.
//   Wave w owns columns [w*NI*256, (w+1)*NI*256); block b owns rows 8b..8b+7.
//   Phase 1: all 8*NI float4 x-loads into registers, FMA per-row partials.
//   Phase 2: 8 interleaved shuffle-reduction chains.
//   Phase 3: lds[8][4] combine, threads 0..7 write out.
// ---------------------------------------------------------------------------
template <int NI>
__global__ __launch_bounds__(256) void clt_slice8nt(
        const float* __restrict__ x,
        const float* __restrict__ A,
        const float* __restrict__ B,
        const float* __restrict__ csum,
        float* __restrict__ out,
        int D) {
    const int lane = threadIdx.x & 63;
    const int w = threadIdx.x >> 6;            // slice id 0..3
    const int colbase = w * (NI * 64);         // slice start, float4 units
    const int rowstride = D >> 2;              // float4 per row

    const f32x4* Av = (const f32x4*)A;
    const f32x4* Bv = (const f32x4*)B;
    f32x4 a4[NI], b4[NI];
#pragma unroll
    for (int i = 0; i < NI; ++i) {
        a4[i] = Av[colbase + i * 64 + lane];   // A/B stay cacheable (reused)
        b4[i] = Bv[colbase + i * 64 + lane];
    }
    const float c = *csum;

    const int r0 = blockIdx.x * 8;
    const f32x4* xv = (const f32x4*)(x + (size_t)r0 * (size_t)D)
                      + colbase + lane;

    // Phase 1: all loads first (nontemporal), then FMAs.
    f32x4 xr[8][NI];
#pragma unroll
    for (int r = 0; r < 8; ++r)
#pragma unroll
        for (int i = 0; i < NI; ++i)
            xr[r][i] = __builtin_nontemporal_load(&xv[(size_t)r * rowstride + i * 64]);

    float acc[8];
#pragma unroll
    for (int r = 0; r < 8; ++r) {
        float p = 0.0f, q = 0.0f;
#pragma unroll
        for (int i = 0; i < NI; ++i) {
            f32x4 xq = xr[r][i];
            p += xq.x * fmaf(a4[i].x, xq.x, b4[i].x);
            q += xq.y * fmaf(a4[i].y, xq.y, b4[i].y);
            p += xq.z * fmaf(a4[i].z, xq.z, b4[i].z);
            q += xq.w * fmaf(a4[i].w, xq.w, b4[i].w);
        }
        acc[r] = p + q;
    }

    // Phase 2: interleaved reductions — 8 independent chains per level.
#pragma unroll
    for (int off = 32; off > 0; off >>= 1) {
#pragma unroll
        for (int r = 0; r < 8; ++r)
            acc[r] += __shfl_down(acc[r], off, 64);
    }

    // Phase 3: cross-wave combine via tiny LDS.
    __shared__ float lds[8][4];
    if (lane == 0) {
#pragma unroll
        for (int r = 0; r < 8; ++r) lds[r][w] = acc[r];
    }
    __syncthreads();
    if (threadIdx.x < 8) {
        out[r0 + threadIdx.x] = lds[threadIdx.x][0] + lds[threadIdx.x][1]
                              + lds[threadIdx.x][2] + lds[threadIdx.x][3]
                              + c;
    }
}

// Generic fallback (any D): block-per-row.
__global__ __launch_bounds__(256) void clt_row_generic(
        const float* __restrict__ x,
        const float* __restrict__ A,
        const float* __restrict__ B,
        const float* __restrict__ csum,
        float* __restrict__ out,
        int D) {
    const int row = blockIdx.x;
    float acc = 0.0f;
    for (int k = threadIdx.x; k < D; k += blockDim.x) {
        float xs = x[(size_t)row * (size_t)D + k];
        acc += xs * fmaf(A[k], xs, B[k]);
    }
    for (int off = 32; off > 0; off >>= 1)
        acc += __shfl_down(acc, off, 64);
    __shared__ float wsum[4];
    if ((threadIdx.x & 63) == 0) wsum[threadIdx.x >> 6] = acc;
    __syncthreads();
    if (threadIdx.x == 0)
        out[row] = wsum[0] + wsum[1] + wsum[2] + wsum[3] + *csum;
}

extern "C" void kernel_launch(void* const* d_in, const int* in_sizes, int n_in,
                              void* d_out, int out_size, void* d_ws, size_t ws_size,
                              hipStream_t stream) {
    const float* x     = (const float*)d_in[0];
    const float* rp    = (const float*)d_in[1];
    const int*   edges = (const int*)d_in[2];
    float* out = (float*)d_out;

    const int D = in_sizes[1] / 2;       // 2048
    const int E = in_sizes[2] / 2;       // D-1
    const int N = out_size;              // 16384 rows

    float* A    = (float*)d_ws;          // [D]
    float* B    = A + D;                 // [D]
    float* csum = B + D;                 // [1]

    clt_prep_kernel<<<1, 1024, D * sizeof(float), stream>>>(rp, edges, A, B, csum, D, E);

    const int NI = D / 1024;             // float4s per lane per slice
    if (N % 8 == 0 && D == NI * 1024 && (NI == 1 || NI == 2 || NI == 4)) {
        const int nblocks = N / 8;       // one 8-row batch per block (2048)
        switch (NI) {
            case 1:  clt_slice8nt<1><<<nblocks, 256, 0, stream>>>(x, A, B, csum, out, D); break;
            case 2:  clt_slice8nt<2><<<nblocks, 256, 0, stream>>>(x, A, B, csum, out, D); break;
            default: clt_slice8nt<4><<<nblocks, 256, 0, stream>>>(x, A, B, csum, out, D); break;
        }
    } else {
        clt_row_generic<<<N, 256, 0, stream>>>(x, A, B, csum, out, D);
    }
}